// Round 2
// baseline (463.022 us; speedup 1.0000x reference)
//
#include <hip/hip_runtime.h>

// MultiHeadSelfAttention: B=4, T=2048, D_MODEL=768, H=12, d_k=64.
// I/O is FP32 (reference dtypes). Compute in bf16 MFMA with fp32 accum.
// Pipeline: [qkv_proj] -> Qp/Kp [bh][t][64] bf16, Vt [bh][d][t] bf16 (transposed)
//           [flash]    -> concat [b][t][768] bf16
//           [oproj]    -> out(fp32) = concat @ Wo^T + bo

#define T_SEQ  2048
#define NH     12
#define DK     64
#define DMODEL 768
#define BATCH  4

typedef __attribute__((ext_vector_type(8))) short short8;   // 8 x bf16 (4 VGPR) MFMA frag
typedef __attribute__((ext_vector_type(4))) float f32x4;    // MFMA C/D frag
typedef __attribute__((ext_vector_type(4))) unsigned short us4;

__device__ __forceinline__ float bf2f(unsigned short u) {
  union { unsigned int i; float f; } x; x.i = ((unsigned int)u) << 16; return x.f;
}
__device__ __forceinline__ unsigned short f2bf(float f) {
  union { float f; unsigned int i; } x; x.f = f;
  unsigned int r = x.i + 0x7fffu + ((x.i >> 16) & 1u);  // RNE
  return (unsigned short)(r >> 16);
}
__device__ __forceinline__ us4 f4_to_bf4(float4 v) {
  us4 r; r.x = f2bf(v.x); r.y = f2bf(v.y); r.z = f2bf(v.z); r.w = f2bf(v.w); return r;
}

// MFMA fragment conventions (guide §3, m89/m91-verified):
//   A-frag: lane holds A[m = lane&15][k = (lane>>4)*8 + j], j=0..7
//   B-frag: lane holds B^T[n = lane&15][k = (lane>>4)*8 + j]  (i.e. B[k][n])
//   C/D:    lane holds D[row = (lane>>4)*4 + reg][col = lane&15]
// All our GEMMs are X @ W^T so W's row-major rows ARE the B-frags.

// ---------------------------------------------------------------------------
// Kernel 1: per-head QKV projection. fp32 in -> bf16 staged -> MFMA.
// grid (32 t-tiles, 48 bh); block 256 = 4 waves, wave handles 16 rows.
// ---------------------------------------------------------------------------
__global__ __launch_bounds__(256, 2)
void qkv_proj_kernel(const float* __restrict__ qin,
                     const float* __restrict__ kin,
                     const float* __restrict__ vin,
                     const float* __restrict__ Wq, const float* __restrict__ bq,
                     const float* __restrict__ Wk, const float* __restrict__ bk,
                     const float* __restrict__ Wv, const float* __restrict__ bv,
                     unsigned short* __restrict__ Qp,   // [bh][t][64]
                     unsigned short* __restrict__ Kp,   // [bh][t][64]
                     unsigned short* __restrict__ Vt)   // [bh][64][t]
{
  const int tt  = blockIdx.x;            // t-tile
  const int bh  = blockIdx.y;
  const int b   = bh / NH, h = bh % NH;
  const int t0  = tt * 64;
  const int tid = threadIdx.x;
  const int wv  = tid >> 6;
  const int ln  = tid & 63;
  const int c   = ln & 15;               // 16-col index
  const int qd  = ln >> 4;               // quad

  __shared__ __align__(16) unsigned short sX[64 * 72];     // input tile (bf16), padded
  __shared__ __align__(16) unsigned short sW[64 * 72];     // weight tile (bf16), padded
  __shared__ __align__(16) unsigned short sVtr[64 * 68];   // [d][t_local], stride 68

  const float* ins[3] = {qin, kin, vin};
  const float* Ws[3]  = {Wq, Wk, Wv};
  const float* bs[3]  = {bq, bk, bv};

#pragma unroll
  for (int p = 0; p < 3; ++p) {
    __syncthreads();  // protect sX/sW reuse across p iterations
    // stage X tile: 64 rows (t0+r), cols h*64..+63 of input [b][t][768]; fp32->bf16
#pragma unroll
    for (int l = 0; l < 4; ++l) {
      int ii = l * 256 + tid;
      int r = ii >> 4, g = ii & 15;
      float4 xv = *reinterpret_cast<const float4*>(ins[p] + ((size_t)(b * T_SEQ + t0 + r)) * DMODEL + h * DK + g * 4);
      *reinterpret_cast<us4*>(&sX[r * 72 + g * 4]) = f4_to_bf4(xv);
      float4 wvv = *reinterpret_cast<const float4*>(Ws[p] + r * DK + g * 4);
      *reinterpret_cast<us4*>(&sW[r * 72 + g * 4]) = f4_to_bf4(wvv);
    }
    __syncthreads();

    short8 af[2];
#pragma unroll
    for (int kc = 0; kc < 2; ++kc)
      af[kc] = *reinterpret_cast<const short8*>(&sX[(wv * 16 + c) * 72 + kc * 32 + qd * 8]);

    f32x4 acc[4];
#pragma unroll
    for (int nb = 0; nb < 4; ++nb) {
      f32x4 a = {0.f, 0.f, 0.f, 0.f};
#pragma unroll
      for (int kc = 0; kc < 2; ++kc) {
        short8 bf = *reinterpret_cast<const short8*>(&sW[(nb * 16 + c) * 72 + kc * 32 + qd * 8]);
        a = __builtin_amdgcn_mfma_f32_16x16x32_bf16(af[kc], bf, a, 0, 0, 0);
      }
      acc[nb] = a;
    }

    if (p < 2) {
      unsigned short* outp = (p == 0) ? Qp : Kp;
#pragma unroll
      for (int nb = 0; nb < 4; ++nb) {
        int n = nb * 16 + c;
        float bias = bs[p][n];
#pragma unroll
        for (int r = 0; r < 4; ++r) {
          int t = t0 + wv * 16 + qd * 4 + r;
          outp[((size_t)bh * T_SEQ + t) * DK + n] = f2bf(acc[nb][r] + bias);
        }
      }
    } else {
      // V: transpose through LDS, emit Vt[bh][d][t] with coalesced 8B stores
#pragma unroll
      for (int nb = 0; nb < 4; ++nb) {
        int n = nb * 16 + c;
        float bias = bs[p][n];
#pragma unroll
        for (int r = 0; r < 4; ++r) {
          int row = wv * 16 + qd * 4 + r;      // t_local
          sVtr[n * 68 + row] = f2bf(acc[nb][r] + bias);
        }
      }
      __syncthreads();
#pragma unroll
      for (int l = 0; l < 4; ++l) {
        int ii = l * 256 + tid;
        int d = ii >> 4, g = ii & 15;
        us4 val = *reinterpret_cast<const us4*>(&sVtr[d * 68 + g * 4]);
        *reinterpret_cast<us4*>(Vt + ((size_t)bh * DK + d) * T_SEQ + t0 + g * 4) = val;
      }
    }
  }
}

// ---------------------------------------------------------------------------
// Kernel 2: flash attention over bf16 intermediates. grid (32, 48); block 256.
// Wave owns 16 Q rows; softmax stats shuffle-reduced within quads (no LDS).
// ---------------------------------------------------------------------------
__global__ __launch_bounds__(256, 2)
void flash_kernel(const unsigned short* __restrict__ Qp,
                  const unsigned short* __restrict__ Kp,
                  const unsigned short* __restrict__ Vt,
                  unsigned short* __restrict__ concat)   // [b][t][768]
{
  const int qt  = blockIdx.x;
  const int bh  = blockIdx.y;
  const int b   = bh / NH, h = bh % NH;
  const int tid = threadIdx.x;
  const int wv  = tid >> 6;
  const int ln  = tid & 63;
  const int c   = ln & 15;
  const int qd  = ln >> 4;

  __shared__ __align__(16) unsigned short sQ[64 * 72];
  __shared__ __align__(16) unsigned short sK[64 * 72];
  __shared__ __align__(16) unsigned short sV[64 * 72];        // V^T tile: [d][p]
  __shared__ __align__(16) unsigned short sP[4][16 * 72];     // per-wave P stripe

  // stage Q tile once
#pragma unroll
  for (int l = 0; l < 4; ++l) {
    int ii = l * 256 + tid;
    int r = ii >> 4, g = ii & 15;
    *reinterpret_cast<us4*>(&sQ[r * 72 + g * 4]) =
        *reinterpret_cast<const us4*>(Qp + ((size_t)bh * T_SEQ + qt * 64 + r) * DK + g * 4);
  }
  __syncthreads();
  short8 qf[2];
  qf[0] = *reinterpret_cast<const short8*>(&sQ[(wv * 16 + c) * 72 + qd * 8]);
  qf[1] = *reinterpret_cast<const short8*>(&sQ[(wv * 16 + c) * 72 + 32 + qd * 8]);

  float m_i[4], l_i[4];
  f32x4 o[4];
#pragma unroll
  for (int r = 0; r < 4; ++r) { m_i[r] = -INFINITY; l_i[r] = 0.f; }
#pragma unroll
  for (int nb = 0; nb < 4; ++nb) o[nb] = (f32x4){0.f, 0.f, 0.f, 0.f};

  const float cexp = 0.125f * 1.44269504088896340736f;  // scale * log2(e)

  for (int j = 0; j < T_SEQ / 64; ++j) {
    __syncthreads();  // previous iteration's frag reads done
#pragma unroll
    for (int l = 0; l < 4; ++l) {
      int ii = l * 256 + tid;
      int r = ii >> 4, g = ii & 15;
      *reinterpret_cast<us4*>(&sK[r * 72 + g * 4]) =
          *reinterpret_cast<const us4*>(Kp + ((size_t)bh * T_SEQ + j * 64 + r) * DK + g * 4);
      *reinterpret_cast<us4*>(&sV[r * 72 + g * 4]) =
          *reinterpret_cast<const us4*>(Vt + ((size_t)bh * DK + r) * T_SEQ + j * 64 + g * 4);
    }
    __syncthreads();

    // S = Q K^T (raw dots; scale folded into exp)
    f32x4 s[4];
#pragma unroll
    for (int nb = 0; nb < 4; ++nb) {
      f32x4 a = {0.f, 0.f, 0.f, 0.f};
#pragma unroll
      for (int kc = 0; kc < 2; ++kc) {
        short8 kf = *reinterpret_cast<const short8*>(&sK[(nb * 16 + c) * 72 + kc * 32 + qd * 8]);
        a = __builtin_amdgcn_mfma_f32_16x16x32_bf16(qf[kc], kf, a, 0, 0, 0);
      }
      s[nb] = a;
    }

    // online softmax; row (qd*4+r) lives on the 16 lanes of quad qd
    float alpha[4];
#pragma unroll
    for (int r = 0; r < 4; ++r) {
      float mx = fmaxf(fmaxf(s[0][r], s[1][r]), fmaxf(s[2][r], s[3][r]));
#pragma unroll
      for (int off = 8; off >= 1; off >>= 1)
        mx = fmaxf(mx, __shfl_xor(mx, off, 64));
      float mnew = fmaxf(m_i[r], mx);
      alpha[r] = exp2f((m_i[r] - mnew) * cexp);
      m_i[r] = mnew;
      float rs = 0.f;
#pragma unroll
      for (int nb = 0; nb < 4; ++nb) {
        float pv = exp2f((s[nb][r] - mnew) * cexp);
        s[nb][r] = pv;
        rs += pv;
      }
#pragma unroll
      for (int off = 8; off >= 1; off >>= 1)
        rs += __shfl_xor(rs, off, 64);
      l_i[r] = l_i[r] * alpha[r] + rs;
    }

    // P: C-layout -> LDS -> A-layout (per-wave region, no barrier needed)
#pragma unroll
    for (int nb = 0; nb < 4; ++nb)
#pragma unroll
      for (int r = 0; r < 4; ++r)
        sP[wv][(qd * 4 + r) * 72 + nb * 16 + c] = f2bf(s[nb][r]);

#pragma unroll
    for (int nb = 0; nb < 4; ++nb)
#pragma unroll
      for (int r = 0; r < 4; ++r)
        o[nb][r] *= alpha[r];

    short8 pf[2];
    pf[0] = *reinterpret_cast<const short8*>(&sP[wv][c * 72 + qd * 8]);
    pf[1] = *reinterpret_cast<const short8*>(&sP[wv][c * 72 + 32 + qd * 8]);
#pragma unroll
    for (int nb = 0; nb < 4; ++nb) {
      short8 vf0 = *reinterpret_cast<const short8*>(&sV[(nb * 16 + c) * 72 + qd * 8]);
      short8 vf1 = *reinterpret_cast<const short8*>(&sV[(nb * 16 + c) * 72 + 32 + qd * 8]);
      o[nb] = __builtin_amdgcn_mfma_f32_16x16x32_bf16(pf[0], vf0, o[nb], 0, 0, 0);
      o[nb] = __builtin_amdgcn_mfma_f32_16x16x32_bf16(pf[1], vf1, o[nb], 0, 0, 0);
    }
  }

  // epilogue: O / l -> concat [b][t][h*64+d]
#pragma unroll
  for (int nb = 0; nb < 4; ++nb) {
#pragma unroll
    for (int r = 0; r < 4; ++r) {
      int t = qt * 64 + wv * 16 + qd * 4 + r;
      float val = o[nb][r] / l_i[r];
      concat[((size_t)(b * T_SEQ + t)) * DMODEL + h * DK + nb * 16 + c] = f2bf(val);
    }
  }
}

// ---------------------------------------------------------------------------
// Kernel 3: out(fp32) = concat(bf16) @ Wo^T(fp32->bf16) + bo(fp32).
// grid (12 n-tiles, 128 m-tiles).
// ---------------------------------------------------------------------------
__global__ __launch_bounds__(256, 2)
void oproj_kernel(const unsigned short* __restrict__ A,    // [8192][768] bf16
                  const float* __restrict__ Wo,            // [768][768] fp32
                  const float* __restrict__ bo,            // [768] fp32
                  float* __restrict__ out)                 // [8192][768] fp32
{
  const int nt  = blockIdx.x;
  const int mt  = blockIdx.y;
  const int tid = threadIdx.x;
  const int wv  = tid >> 6;
  const int ln  = tid & 63;
  const int c   = ln & 15;
  const int qd  = ln >> 4;

  __shared__ __align__(16) unsigned short sA[64 * 72];
  __shared__ __align__(16) unsigned short sB[64 * 72];

  f32x4 acc[4];
#pragma unroll
  for (int nb = 0; nb < 4; ++nb) acc[nb] = (f32x4){0.f, 0.f, 0.f, 0.f};

  for (int kk = 0; kk < DMODEL / 64; ++kk) {
    __syncthreads();
#pragma unroll
    for (int l = 0; l < 4; ++l) {
      int ii = l * 256 + tid;
      int r = ii >> 4, g = ii & 15;
      *reinterpret_cast<us4*>(&sA[r * 72 + g * 4]) =
          *reinterpret_cast<const us4*>(A + ((size_t)(mt * 64 + r)) * DMODEL + kk * 64 + g * 4);
      float4 wv4 = *reinterpret_cast<const float4*>(Wo + ((size_t)(nt * 64 + r)) * DMODEL + kk * 64 + g * 4);
      *reinterpret_cast<us4*>(&sB[r * 72 + g * 4]) = f4_to_bf4(wv4);
    }
    __syncthreads();

    short8 af0 = *reinterpret_cast<const short8*>(&sA[(wv * 16 + c) * 72 + qd * 8]);
    short8 af1 = *reinterpret_cast<const short8*>(&sA[(wv * 16 + c) * 72 + 32 + qd * 8]);
#pragma unroll
    for (int nb = 0; nb < 4; ++nb) {
      short8 b0 = *reinterpret_cast<const short8*>(&sB[(nb * 16 + c) * 72 + qd * 8]);
      short8 b1 = *reinterpret_cast<const short8*>(&sB[(nb * 16 + c) * 72 + 32 + qd * 8]);
      acc[nb] = __builtin_amdgcn_mfma_f32_16x16x32_bf16(af0, b0, acc[nb], 0, 0, 0);
      acc[nb] = __builtin_amdgcn_mfma_f32_16x16x32_bf16(af1, b1, acc[nb], 0, 0, 0);
    }
  }

#pragma unroll
  for (int nb = 0; nb < 4; ++nb) {
    int n = nt * 64 + nb * 16 + c;
    float bias = bo[n];
#pragma unroll
    for (int r = 0; r < 4; ++r) {
      int m = mt * 64 + wv * 16 + qd * 4 + r;
      out[(size_t)m * DMODEL + n] = acc[nb][r] + bias;
    }
  }
}

// ---------------------------------------------------------------------------
extern "C" void kernel_launch(void* const* d_in, const int* in_sizes, int n_in,
                              void* d_out, int out_size, void* d_ws, size_t ws_size,
                              hipStream_t stream) {
  const float* q  = (const float*)d_in[0];
  const float* k  = (const float*)d_in[1];
  const float* v  = (const float*)d_in[2];
  const float* Wq = (const float*)d_in[3];
  const float* bq = (const float*)d_in[4];
  const float* Wk = (const float*)d_in[5];
  const float* bk = (const float*)d_in[6];
  const float* Wv = (const float*)d_in[7];
  const float* bv = (const float*)d_in[8];
  const float* Wo = (const float*)d_in[9];
  const float* bo = (const float*)d_in[10];

  const size_t NTOK = (size_t)BATCH * T_SEQ;          // 8192
  const size_t PER  = NTOK * DK * NH;                 // 6291456 elems
  unsigned short* Qp     = (unsigned short*)d_ws;
  unsigned short* Kp     = Qp + PER;
  unsigned short* Vt     = Kp + PER;
  unsigned short* concat = Vt + PER;                  // total 48 MB bf16

  dim3 blk(256);
  qkv_proj_kernel<<<dim3(32, BATCH * NH), blk, 0, stream>>>(q, k, v, Wq, bq, Wk, bk, Wv, bv, Qp, Kp, Vt);
  flash_kernel<<<dim3(32, BATCH * NH), blk, 0, stream>>>(Qp, Kp, Vt, concat);
  oproj_kernel<<<dim3(12, 128), blk, 0, stream>>>(concat, Wo, bo, (float*)d_out);
}